// Round 4
// baseline (414.047 us; speedup 1.0000x reference)
//
#include <hip/hip_runtime.h>
#include <hip/hip_bf16.h>

typedef __bf16 bf16;
typedef __attribute__((ext_vector_type(8))) __bf16 bf16x8;
typedef __attribute__((ext_vector_type(4))) __bf16 bf16x4;
typedef __attribute__((ext_vector_type(4))) float f32x4;

#define NTOK 98
#define NP   112
#define DIM  128
#define HD   32
#define SCALE_Q 0.17677669529663687f

#define SXP 136     // sX/sO row stride (bf16)
#define SPP 136     // per-wave P-staging row stride
#define TSP 40      // per-wave transpose-scratch row stride (80 B: 16B-aligned b128 reads)

// ws layout (bytes) — total ~11.4 MB
#define WS_WTQ 0ULL                    // bf16 [384][128]            98304
#define WS_PT  98304ULL                // bf16 [128][128]            32768
#define WS_BM  131072ULL               // f32  [64][4][98][112]   11239424

__global__ __launch_bounds__(256) void prep2_kernel(
    const float* __restrict__ qkv_w, const float* __restrict__ proj_w,
    bf16* __restrict__ WTq, bf16* __restrict__ PT)
{
  int i = blockIdx.x * 256 + threadIdx.x;
  if (i < 384*128) {
    int n = i >> 7, k = i & 127;
    WTq[i] = (bf16)qkv_w[k*384 + n];
  } else if (i < 384*128 + 128*128) {
    int j = i - 384*128; int n = j >> 7, k = j & 127;
    PT[j] = (bf16)proj_w[k*128 + n];
  }
}

// bm2[w][h][col][row(112 pad)] = table[rel[row*98+col]][h] + mask[w][row][col]
__global__ __launch_bounds__(256) void bm_kernel(
    const float* __restrict__ table, const int* __restrict__ rel,
    const float* __restrict__ mask, float* __restrict__ bm2)
{
  int g = blockIdx.x * 256 + threadIdx.x;
  if (g >= 64*4*98*112) return;
  int row = g % 112;
  int rest = g / 112;
  int col = rest % 98;
  int rest2 = rest / 98;
  int h = rest2 & 3;
  int w = rest2 >> 2;
  float v = 0.f;
  if (row < 98) {
    int ij = row*98 + col;
    v = table[rel[ij]*4 + h] + mask[w*9604 + ij];
  }
  bm2[g] = v;
}

// One block = one window (256 thr, 4 waves, wave = head). LDS 47.9 KB -> 3 blocks/CU.
__global__ __launch_bounds__(256, 3) void fused_attn_kernel(
    const float* __restrict__ x, const float* __restrict__ qkv_b,
    const float* __restrict__ proj_b, const bf16* __restrict__ WTq,
    const bf16* __restrict__ PT, const float* __restrict__ bm2,
    float* __restrict__ out)
{
  __shared__ bf16 sX[NP*SXP];        // x (bf16); becomes O after barrier 2
  __shared__ bf16 sPs[4*16*SPP];     // per-wave: phase-2 transpose scratch, then P staging

  const int b = blockIdx.x, w = b & 63;
  const int tid = threadIdx.x;
  const int wave = tid >> 6, lane = tid & 63;
  const int quad = lane >> 4, l16 = lane & 15;
  const int h = wave;
  const f32x4 fzero = {0.f, 0.f, 0.f, 0.f};
  const f32x4 fneg = {-1.0e30f, -1.0e30f, -1.0e30f, -1.0e30f};

  // ---------- phase 1: stage x -> bf16 LDS, zero pad rows ----------
  {
    const float* xb = x + (size_t)b * (NTOK*DIM);
    for (int i = tid; i < NTOK*32; i += 256) {
      int row = i >> 5, c4 = (i & 31) << 2;
      const float4 v = *(const float4*)(xb + row*DIM + c4);
      bf16x4 pk; pk[0]=(bf16)v.x; pk[1]=(bf16)v.y; pk[2]=(bf16)v.z; pk[3]=(bf16)v.w;
      *(bf16x4*)&sX[row*SXP + c4] = pk;
    }
    for (int i = tid; i < 14*32; i += 256) {
      int row = NTOK + (i >> 5), c4 = (i & 31) << 2;
      uint2 z; z.x = 0; z.y = 0;
      *(uint2*)&sX[row*SXP + c4] = z;
    }
  }
  __syncthreads();

  bf16* scr = sPs + wave*16*SPP;   // per-wave scratch (4352 B available)

  // ---------- phase 2: per-wave head h computes K, V, Q into register fragments ----------
  // K fragments: bk[nt] = B[n=tok=l16 of tile nt][k=dim=quad*8+j]
  bf16x8 bk[7];
  {
    bf16x8 wf[2][4]; float cb[2];
#pragma unroll
    for (int half = 0; half < 2; ++half) {
      const int ncol = DIM + h*HD + half*16 + l16;
#pragma unroll
      for (int ks = 0; ks < 4; ++ks)
        wf[half][ks] = *(const bf16x8*)(WTq + ncol*DIM + ks*32 + quad*8);
      cb[half] = qkv_b[ncol];
    }
#pragma unroll
    for (int mt = 0; mt < 7; ++mt) {
#pragma unroll
      for (int half = 0; half < 2; ++half) {
        f32x4 acc = fzero;
#pragma unroll
        for (int ks = 0; ks < 4; ++ks) {
          const bf16x8 a = *(const bf16x8*)&sX[(mt*16 + l16)*SXP + ks*32 + quad*8];
          acc = __builtin_amdgcn_mfma_f32_16x16x32_bf16(a, wf[half][ks], acc, 0, 0, 0);
        }
        // C layout (row=tok=quad*4+r, col=dim=l16) -> scratch [tok16][dim 32 (TSP pad)]
#pragma unroll
        for (int r = 0; r < 4; ++r)
          scr[(quad*4 + r)*TSP + half*16 + l16] = (bf16)(acc[r] + cb[half]);
      }
      bk[mt] = *(const bf16x8*)&scr[l16*TSP + quad*8];
    }
  }

  // V^T fragments: bv[dt][ks] = B[n=dim=dt*16+l16][k=tok=ks*32+quad*8+j]
  bf16x8 bv[2][4];
  {
    bf16x8 wf[2][4]; float cb[2];
#pragma unroll
    for (int half = 0; half < 2; ++half) {
      const int ncol = 2*DIM + h*HD + half*16 + l16;
#pragma unroll
      for (int ks = 0; ks < 4; ++ks)
        wf[half][ks] = *(const bf16x8*)(WTq + ncol*DIM + ks*32 + quad*8);
      cb[half] = qkv_b[ncol];
    }
#pragma unroll
    for (int ks2 = 0; ks2 < 4; ++ks2) {        // token chunks of 32
#pragma unroll
      for (int sub = 0; sub < 2; ++sub) {
        const int mt = ks2*2 + sub;
        if (mt < 7) {
#pragma unroll
          for (int half = 0; half < 2; ++half) {
            f32x4 acc = fzero;
#pragma unroll
            for (int ks = 0; ks < 4; ++ks) {
              const bf16x8 a = *(const bf16x8*)&sX[(mt*16 + l16)*SXP + ks*32 + quad*8];
              acc = __builtin_amdgcn_mfma_f32_16x16x32_bf16(a, wf[half][ks], acc, 0, 0, 0);
            }
            // transposed store: scratch [dim 32][tok 32 (TSP pad)], 4 consecutive toks
            bf16x4 pk;
#pragma unroll
            for (int r = 0; r < 4; ++r) pk[r] = (bf16)(acc[r] + cb[half]);
            *(bf16x4*)&scr[(half*16 + l16)*TSP + sub*16 + quad*4] = pk;
          }
        } else {
          // toks 112..127: zero-fill (avoid NaN garbage; P is 0 there but 0*NaN=NaN)
          const int dim = lane >> 1, part = lane & 1;
          uint4 z; z.x = 0; z.y = 0; z.z = 0; z.w = 0;
          *(uint4*)&scr[dim*TSP + 16 + part*8] = z;
        }
      }
#pragma unroll
      for (int dt = 0; dt < 2; ++dt)
        bv[dt][ks2] = *(const bf16x8*)&scr[(dt*16 + l16)*TSP + quad*8];
    }
  }

  // Q fragments (pre-scaled): aq[mt] = A[m=tok=l16][k=dim=quad*8+j]
  bf16x8 aq[7];
  {
    bf16x8 wf[2][4]; float cb[2];
#pragma unroll
    for (int half = 0; half < 2; ++half) {
      const int ncol = h*HD + half*16 + l16;
#pragma unroll
      for (int ks = 0; ks < 4; ++ks)
        wf[half][ks] = *(const bf16x8*)(WTq + ncol*DIM + ks*32 + quad*8);
      cb[half] = qkv_b[ncol];
    }
#pragma unroll
    for (int mt = 0; mt < 7; ++mt) {
#pragma unroll
      for (int half = 0; half < 2; ++half) {
        f32x4 acc = fzero;
#pragma unroll
        for (int ks = 0; ks < 4; ++ks) {
          const bf16x8 a = *(const bf16x8*)&sX[(mt*16 + l16)*SXP + ks*32 + quad*8];
          acc = __builtin_amdgcn_mfma_f32_16x16x32_bf16(a, wf[half][ks], acc, 0, 0, 0);
        }
#pragma unroll
        for (int r = 0; r < 4; ++r)
          scr[(quad*4 + r)*TSP + half*16 + l16] = (bf16)((acc[r] + cb[half]) * SCALE_Q);
      }
      aq[mt] = *(const bf16x8*)&scr[l16*TSP + quad*8];
    }
  }

  // barrier 2: all waves done reading sX -> sX region becomes sO
  __syncthreads();

  // ---------- phase 3: attention (no block barriers inside) ----------
  bf16* sP = scr;
  {   // zero P pad cols 112..127 (16 rows x 16 cols, 4 bf16 per lane)
    int row = lane >> 2, c0 = 112 + ((lane & 3) << 2);
    uint2 z; z.x = 0; z.y = 0;
    *(uint2*)&sP[row*SPP + c0] = z;
  }
  const float* bmh = bm2 + (size_t)(w*4 + h)*(98*NP);

#pragma unroll 1
  for (int mt = 0; mt < 7; ++mt) {
    f32x4 s[7];
#pragma unroll
    for (int nt = 0; nt < 7; ++nt)
      s[nt] = __builtin_amdgcn_mfma_f32_16x16x32_bf16(aq[mt], bk[nt], fzero, 0, 0, 0);
#pragma unroll
    for (int nt = 0; nt < 7; ++nt) {
      const int col = nt*16 + l16;
      if (col < NTOK) {
        const f32x4 bmv = *(const f32x4*)(bmh + col*NP + mt*16 + quad*4);
        s[nt] = s[nt] + bmv;
      } else {
        s[nt] = fneg;
      }
    }
    // row softmax (rows live in 16-lane groups)
#pragma unroll
    for (int r = 0; r < 4; ++r) {
      const int row = mt*16 + quad*4 + r;
      const bool rowok = row < NTOK;
      float sv[7];
      float mx = -3.0e38f;
#pragma unroll
      for (int nt = 0; nt < 7; ++nt) {
        float v = rowok ? s[nt][r] : -1.0e30f;
        sv[nt] = v;
        mx = fmaxf(mx, v);
      }
#pragma unroll
      for (int off = 1; off < 16; off <<= 1)
        mx = fmaxf(mx, __shfl_xor(mx, off, 64));
      float sum = 0.f;
#pragma unroll
      for (int nt = 0; nt < 7; ++nt) {
        const float p = __expf(sv[nt] - mx);
        sv[nt] = p;
        sum += p;
      }
#pragma unroll
      for (int off = 1; off < 16; off <<= 1)
        sum += __shfl_xor(sum, off, 64);
      const float inv = __builtin_amdgcn_rcpf(sum);
#pragma unroll
      for (int nt = 0; nt < 7; ++nt)
        sP[(quad*4 + r)*SPP + nt*16 + l16] = (bf16)(sv[nt] * inv);
    }
    // O-tile = P V
    f32x4 o0 = fzero, o1 = fzero;
#pragma unroll
    for (int ks = 0; ks < 4; ++ks) {
      const bf16x8 ap = *(const bf16x8*)&sP[l16*SPP + ks*32 + quad*8];
      o0 = __builtin_amdgcn_mfma_f32_16x16x32_bf16(ap, bv[0][ks], o0, 0, 0, 0);
      o1 = __builtin_amdgcn_mfma_f32_16x16x32_bf16(ap, bv[1][ks], o1, 0, 0, 0);
    }
    // O into sX region (per-wave disjoint columns h*32..h*32+31)
#pragma unroll
    for (int r = 0; r < 4; ++r) {
      sX[(mt*16 + quad*4 + r)*SXP + h*HD + l16]      = (bf16)o0[r];
      sX[(mt*16 + quad*4 + r)*SXP + h*HD + 16 + l16] = (bf16)o1[r];
    }
  }
  __syncthreads();   // barrier 3: O complete

  // ---------- phase 4: proj GEMM + store; wave does col-tiles {wave, wave+4} ----------
  float* outb = out + (size_t)b * (NTOK*DIM);
#pragma unroll
  for (int nn = 0; nn < 2; ++nn) {
    const int nt2 = wave + nn*4;
    bf16x8 pf[4];
#pragma unroll
    for (int ks = 0; ks < 4; ++ks)
      pf[ks] = *(const bf16x8*)(PT + (nt2*16 + l16)*DIM + ks*32 + quad*8);
    const float pb = proj_b[nt2*16 + l16];
#pragma unroll
    for (int mt = 0; mt < 7; ++mt) {
      f32x4 acc = fzero;
#pragma unroll
      for (int ks = 0; ks < 4; ++ks) {
        const bf16x8 a = *(const bf16x8*)&sX[(mt*16 + l16)*SXP + ks*32 + quad*8];
        acc = __builtin_amdgcn_mfma_f32_16x16x32_bf16(a, pf[ks], acc, 0, 0, 0);
      }
#pragma unroll
      for (int r = 0; r < 4; ++r) {
        const int row = mt*16 + quad*4 + r;
        if (row < NTOK)
          outb[row*DIM + nt2*16 + l16] = acc[r] + pb;
      }
    }
  }
}

extern "C" void kernel_launch(void* const* d_in, const int* in_sizes, int n_in,
                              void* d_out, int out_size, void* d_ws, size_t ws_size,
                              hipStream_t stream)
{
  const float* x      = (const float*)d_in[0];
  const float* mask   = (const float*)d_in[1];
  const float* qkv_w  = (const float*)d_in[2];
  const float* qkv_b  = (const float*)d_in[3];
  const float* table  = (const float*)d_in[4];
  const int*   rel    = (const int*)d_in[5];
  const float* proj_w = (const float*)d_in[6];
  const float* proj_b = (const float*)d_in[7];
  float* out = (float*)d_out;
  char* ws = (char*)d_ws;

  bf16*  WTq = (bf16*)(ws + WS_WTQ);
  bf16*  PT  = (bf16*)(ws + WS_PT);
  float* bm2 = (float*)(ws + WS_BM);

  prep2_kernel<<<(384*128 + 128*128 + 255)/256, 256, 0, stream>>>(qkv_w, proj_w, WTq, PT);
  bm_kernel<<<(64*4*98*112 + 255)/256, 256, 0, stream>>>(table, rel, mask, bm2);
  fused_attn_kernel<<<2048, 256, 0, stream>>>(x, qkv_b, proj_b, WTq, PT, bm2, out);
}